// Round 4
// baseline (236.987 us; speedup 1.0000x reference)
//
#include <hip/hip_runtime.h>
#include <stdint.h>

// ---------------------------------------------------------------------------
// SparseAttention: B=1 S=4096 D=1024 H=16 HD=64, BLOCK=128 C=32
// cvt_x -> tpose4 -> gemm_bt<0>(QKV, q pre-scaled by 0.125*log2e) ->
// attn_kernel (split-K jobs, partial O/m/l for b>=8) -> attn_merge -> gemm_bt<1>
// Softmax is base-2 (exp2) throughout. LDS XOR-swizzled on 16B granules.
// ---------------------------------------------------------------------------

#define S_LEN 4096

typedef __bf16 bf16x8 __attribute__((ext_vector_type(8)));
typedef float  f32x4  __attribute__((ext_vector_type(4)));

__device__ __forceinline__ uint16_t f2bf(float f) {
    uint32_t u = __builtin_bit_cast(uint32_t, f);
    u += 0x7fffu + ((u >> 16) & 1u);   // RNE
    return (uint16_t)(u >> 16);
}
__device__ __forceinline__ float bf2f(uint16_t v) {
    uint32_t u = (uint32_t)v << 16;
    return __builtin_bit_cast(float, u);
}
__device__ __forceinline__ uint32_t pack2bf(float lo, float hi) {
    return (uint32_t)f2bf(lo) | ((uint32_t)f2bf(hi) << 16);
}
__device__ __forceinline__ void gload_lds16(const uint16_t* g, uint16_t* l) {
    __builtin_amdgcn_global_load_lds(
        (const __attribute__((address_space(1))) void*)g,
        (__attribute__((address_space(3))) void*)l, 16, 0, 0);
}

// gather-key mapping: chunk ch (64 keys), local key kl
__device__ __forceinline__ int key_of(int b, int ngc, int ch, int kl) {
    if (ch >= ngc) return b * 128 + (ch - ngc) * 64 + kl;   // own block
    int t = ch * 64 + kl;                                    // prev-block gather
    int kb = t / 33, rr = t - kb * 33;
    return kb * 128 + (rr == 0 ? 0 : 95 + rr);
}

// ---------------- x fp32 -> bf16 -------------------------------------------
__global__ __launch_bounds__(256) void cvt_x_kernel(const float* __restrict__ x,
                                                    uint16_t* __restrict__ xb) {
    int i = (blockIdx.x * 256 + threadIdx.x) * 4;
    const float4 v = *(const float4*)(x + i);
    ushort4 o;
    o.x = f2bf(v.x); o.y = f2bf(v.y); o.z = f2bf(v.z); o.w = f2bf(v.w);
    *(ushort4*)(xb + i) = o;
}

// ---------------- W [K=1024][N=1024] fp32 -> [N][K] bf16 -------------------
__global__ __launch_bounds__(256) void tpose4(const float* __restrict__ Wq,
                                              const float* __restrict__ Wk,
                                              const float* __restrict__ Wv,
                                              const float* __restrict__ Wo,
                                              uint16_t* __restrict__ wqkvt,
                                              uint16_t* __restrict__ wot) {
    __shared__ float tile[64][65];
    const int z = blockIdx.z;
    const float* src = (z == 0) ? Wq : (z == 1) ? Wk : (z == 2) ? Wv : Wo;
    uint16_t* dst = (z < 3) ? (wqkvt + (size_t)z * 1024 * 1024) : wot;
    const int ro = blockIdx.y * 64, co = blockIdx.x * 64;
    const int c = threadIdx.x & 63, r4 = threadIdx.x >> 6;
#pragma unroll
    for (int i = 0; i < 16; i++) {
        int r = i * 4 + r4;
        tile[r][c] = src[(size_t)(ro + r) * 1024 + co + c];
    }
    __syncthreads();
#pragma unroll
    for (int i = 0; i < 16; i++) {
        int cc = i * 4 + r4;
        dst[(size_t)(co + cc) * 1024 + ro + c] = f2bf(tile[c][cc]);
    }
}

// ---------------- GEMM: C[M][N] = A[M][1024] * Bt[N][1024]^T ---------------
template <int MODE>
__global__ __launch_bounds__(256) void gemm_bt(const uint16_t* __restrict__ A,
                                               const uint16_t* __restrict__ Bt,
                                               const float* __restrict__ bias0,
                                               const float* __restrict__ bias1,
                                               const float* __restrict__ bias2,
                                               uint16_t* __restrict__ Cb,
                                               float* __restrict__ Cf) {
    __shared__ __attribute__((aligned(16))) uint16_t As[128 * 64];
    __shared__ __attribute__((aligned(16))) uint16_t Bs[128 * 64];
    const int tid = threadIdx.x;
    const int wave = tid >> 6, lane = tid & 63;
    const int quad = lane >> 4, l16 = lane & 15;
    const int row0 = blockIdx.y * 128, col0 = blockIdx.x * 128;
    const int wm = (wave >> 1) * 64, wn = (wave & 1) * 64;
    const int srow = lane >> 3, scol = lane & 7;
    const int gcol = (scol ^ srow) * 8;
    const int sw = (l16 & 7);

    f32x4 acc[4][4];
    const f32x4 z4 = {0.f, 0.f, 0.f, 0.f};
#pragma unroll
    for (int i = 0; i < 4; i++)
#pragma unroll
        for (int j = 0; j < 4; j++) acc[i][j] = z4;

    for (int k0 = 0; k0 < 1024; k0 += 64) {
        __syncthreads();
#pragma unroll
        for (int i = 0; i < 4; i++) {
            int u = wave * 4 + i;
            int row = u * 8 + srow;
            gload_lds16(A  + (size_t)(row0 + row) * 1024 + k0 + gcol, As + u * 512);
            gload_lds16(Bt + (size_t)(col0 + row) * 1024 + k0 + gcol, Bs + u * 512);
        }
        __syncthreads();
#pragma unroll
        for (int kk = 0; kk < 2; kk++) {
            bf16x8 af[4], bfr[4];
#pragma unroll
            for (int mt = 0; mt < 4; mt++)
                af[mt] = *(const bf16x8*)(As + (wm + mt * 16 + l16) * 64 + ((kk * 4 + quad) ^ sw) * 8);
#pragma unroll
            for (int nt = 0; nt < 4; nt++)
                bfr[nt] = *(const bf16x8*)(Bs + (wn + nt * 16 + l16) * 64 + ((kk * 4 + quad) ^ sw) * 8);
#pragma unroll
            for (int mt = 0; mt < 4; mt++)
#pragma unroll
                for (int nt = 0; nt < 4; nt++) {
                    if (MODE == 0)   // C^T orientation: reg index = n
                        acc[mt][nt] = __builtin_amdgcn_mfma_f32_16x16x32_bf16(
                            bfr[nt], af[mt], acc[mt][nt], 0, 0, 0);
                    else
                        acc[mt][nt] = __builtin_amdgcn_mfma_f32_16x16x32_bf16(
                            af[mt], bfr[nt], acc[mt][nt], 0, 0, 0);
                }
        }
    }

    if (MODE == 0) {
#pragma unroll
        for (int nt = 0; nt < 4; nt++) {
            int n = col0 + wn + nt * 16 + quad * 4;
            int which = n >> 10, c = n & 1023;
            const float* bp = (which == 0) ? bias0 : (which == 1 ? bias1 : bias2);
            const float4 b4 = *(const float4*)(bp + c);
            // q pre-scaled by 1/sqrt(64) * log2(e) for base-2 softmax
            float scv = (which == 0) ? 0.18033688f : 1.0f;
            uint16_t* op = Cb + (size_t)which * S_LEN * 1024 + c;
#pragma unroll
            for (int mt = 0; mt < 4; mt++) {
                int s = row0 + wm + mt * 16 + l16;
                ushort4 pkv;
                pkv.x = f2bf((acc[mt][nt][0] + b4.x) * scv);
                pkv.y = f2bf((acc[mt][nt][1] + b4.y) * scv);
                pkv.z = f2bf((acc[mt][nt][2] + b4.z) * scv);
                pkv.w = f2bf((acc[mt][nt][3] + b4.w) * scv);
                *(ushort4*)(op + (size_t)s * 1024) = pkv;
            }
        }
    } else {
#pragma unroll
        for (int nt = 0; nt < 4; nt++) {
            int n = col0 + wn + nt * 16 + l16;
            float bi = bias0[n];
#pragma unroll
            for (int mt = 0; mt < 4; mt++) {
                int row = row0 + wm + mt * 16 + quad * 4;
#pragma unroll
                for (int r = 0; r < 4; r++)
                    Cf[(size_t)(row + r) * 1024 + n] = acc[mt][nt][r] + bi;
            }
        }
    }
}

// ---------------- sparse flash attention (v3, split-K jobs) ----------------
// grid (56 jobs, 16 heads) x 256 thr (4 waves, 32 q each).
// bjob<8: b=bjob, all chunks, write normalized ctx.
// bjob>=8: idx=bjob-8, b=8+(idx>>1), half=idx&1 chunk range; write partial
// (bf16 unnormalized O + f32 m,l base-2) at slot=idx*16+h.
__global__ __launch_bounds__(256, 4) void attn_kernel(const uint16_t* __restrict__ Qg,
                                                      const uint16_t* __restrict__ Kg,
                                                      const uint16_t* __restrict__ Vg,
                                                      uint16_t* __restrict__ Og,
                                                      uint16_t* __restrict__ pO,
                                                      float2* __restrict__ pStats) {
    __shared__ __attribute__((aligned(16))) uint16_t SM[20480];  // 40 KiB
    uint16_t* Kb = SM;            // 2 x [64][64]   16 KiB (double buffer)
    uint16_t* Vt = SM + 8192;     // [hd64][key64]   8 KiB
    uint16_t* Pb = SM + 12288;    // 4 x [32][64]   16 KiB (per-wave)

    const int h = blockIdx.y;
    const int bjob = blockIdx.x;
    int b, slot;
    if (bjob < 8) { b = bjob; slot = -1; }
    else { int idx = bjob - 8; b = 8 + (idx >> 1); slot = idx * 16 + h; }
    const int nprev = 33 * b;
    const int ngc = (nprev + 63) >> 6;
    const int ntot = ngc + 2;
    int cbeg = 0, cend = ntot;
    if (bjob >= 8) {
        int mid = (ntot + 1) >> 1;
        if ((bjob - 8) & 1) cbeg = mid; else cend = mid;
    }
    const size_t hoff = (size_t)h * 64;

    const int tid = threadIdx.x;
    const int wave = tid >> 6, lane = tid & 63;
    const int quad = lane >> 4, l16 = lane & 15;
    const int sw = l16 & 7;
    const int gCol = ((lane & 7) ^ ((lane >> 3) & 7)) * 8;
    const int kp = tid & 31, hseg = tid >> 5;   // V stager coords

    // ---- Q fragments in registers (B-operand layout, 32 q per wave)
    bf16x8 qb[2][2];
#pragma unroll
    for (int kk = 0; kk < 2; kk++)
#pragma unroll
        for (int qt = 0; qt < 2; qt++) {
            uint4 t = *(const uint4*)(Qg + (size_t)(b * 128 + wave * 32 + qt * 16 + l16) * 1024
                                      + hoff + kk * 32 + quad * 8);
            qb[kk][qt] = __builtin_bit_cast(bf16x8, t);
        }

    // ---- stage K(cbeg) into buf0
#pragma unroll
    for (int i = 0; i < 2; i++) {
        int u = wave * 2 + i;
        int row = u * 8 + (lane >> 3);
        int key = key_of(b, ngc, cbeg, row);
        gload_lds16(Kg + (size_t)key * 1024 + hoff + gCol, Kb + u * 512);
    }
    __syncthreads();

    float m_run[2] = {-3e38f, -3e38f}, l_run[2] = {0.f, 0.f};
    f32x4 o[4][2];
    const f32x4 z4 = {0.f, 0.f, 0.f, 0.f};
#pragma unroll
    for (int mt = 0; mt < 4; mt++) { o[mt][0] = z4; o[mt][1] = z4; }

    uint16_t* Pw = Pb + wave * 2048;
    int cur = 0;

    for (int ci = cbeg; ci < cend; ci++) {
        // (1) V gather for this chunk -> regs (2 keys x 8 hd per thread)
        int vk0 = key_of(b, ngc, ci, 2 * kp);
        int vk1 = key_of(b, ngc, ci, 2 * kp + 1);
        uint4 va4 = *(const uint4*)(Vg + (size_t)vk0 * 1024 + hoff + hseg * 8);
        uint4 vc4 = *(const uint4*)(Vg + (size_t)vk1 * 1024 + hoff + hseg * 8);

        // (2) async K prefetch for next chunk -> other buffer
        if (ci + 1 < cend) {
#pragma unroll
            for (int i = 0; i < 2; i++) {
                int u = wave * 2 + i;
                int row = u * 8 + (lane >> 3);
                int key = key_of(b, ngc, ci + 1, row);
                gload_lds16(Kg + (size_t)key * 1024 + hoff + gCol,
                            Kb + (cur ^ 1) * 4096 + u * 512);
            }
        }

        // (3) S^T = K.Q^T (C: col=q=l16, row=key)
        const uint16_t* Kc = Kb + cur * 4096;
        f32x4 s[4][2];
#pragma unroll
        for (int kt = 0; kt < 4; kt++) { s[kt][0] = z4; s[kt][1] = z4; }
#pragma unroll
        for (int kk = 0; kk < 2; kk++) {
            bf16x8 ka[4];
#pragma unroll
            for (int kt = 0; kt < 4; kt++)
                ka[kt] = *(const bf16x8*)(Kc + (kt * 16 + l16) * 64 + ((kk * 4 + quad) ^ sw) * 8);
#pragma unroll
            for (int kt = 0; kt < 4; kt++)
#pragma unroll
                for (int qt = 0; qt < 2; qt++)
                    s[kt][qt] = __builtin_amdgcn_mfma_f32_16x16x32_bf16(
                        ka[kt], qb[kk][qt], s[kt][qt], 0, 0, 0);
        }

        // masking
        if (ci >= ngc) {
            int cb = ci - ngc;
#pragma unroll
            for (int kt = 0; kt < 4; kt++) {
                int keyl = cb * 64 + kt * 16 + quad * 4;
#pragma unroll
                for (int qt = 0; qt < 2; qt++) {
                    int ql = wave * 32 + qt * 16 + l16;
#pragma unroll
                    for (int r = 0; r < 4; r++)
                        if (keyl + r > ql) s[kt][qt][r] = -1e30f;
                }
            }
        } else if (ci == ngc - 1) {
#pragma unroll
            for (int kt = 0; kt < 4; kt++) {
                int tg = ci * 64 + kt * 16 + quad * 4;
#pragma unroll
                for (int r = 0; r < 4; r++)
                    if (tg + r >= nprev) { s[kt][0][r] = -1e30f; s[kt][1][r] = -1e30f; }
            }
        }

        // (4) online softmax (base-2), pack P
        uint32_t pk[4][2][2];
        float al[2];
#pragma unroll
        for (int qt = 0; qt < 2; qt++) {
            float mx = -3e38f;
#pragma unroll
            for (int kt = 0; kt < 4; kt++)
#pragma unroll
                for (int r = 0; r < 4; r++) mx = fmaxf(mx, s[kt][qt][r]);
            mx = fmaxf(mx, __shfl_xor(mx, 16));
            mx = fmaxf(mx, __shfl_xor(mx, 32));
            float mn = fmaxf(m_run[qt], mx);
            float sub = fmaxf(mn, -1e20f);
            al[qt] = exp2f(m_run[qt] - sub);
            m_run[qt] = mn;
            float ps = 0.f;
#pragma unroll
            for (int kt = 0; kt < 4; kt++) {
                float p0 = exp2f(s[kt][qt][0] - sub);
                float p1 = exp2f(s[kt][qt][1] - sub);
                float p2 = exp2f(s[kt][qt][2] - sub);
                float p3 = exp2f(s[kt][qt][3] - sub);
                ps += (p0 + p1) + (p2 + p3);
                pk[kt][qt][0] = pack2bf(p0, p1);
                pk[kt][qt][1] = pack2bf(p2, p3);
            }
            ps += __shfl_xor(ps, 16);
            ps += __shfl_xor(ps, 32);
            l_run[qt] = l_run[qt] * al[qt] + ps;
        }

        // (5) P -> per-wave LDS ([q32][key64], swizzled 16B granules)
#pragma unroll
        for (int qt = 0; qt < 2; qt++) {
            int row = qt * 16 + l16;
            int rs = row & 7;
#pragma unroll
            for (int kt = 0; kt < 4; kt++) {
                int g = kt * 2 + (quad >> 1);
                uint2 val = make_uint2(pk[kt][qt][0], pk[kt][qt][1]);
                *(uint2*)(Pw + row * 64 + ((g ^ rs) * 8) + (quad & 1) * 4) = val;
            }
        }

        __syncthreads();   // (A) prior PV reads of Vt done

        // (6) V^T writes: interleave key pairs, b32 stores (conflict-free)
        {
            uint32_t av[4] = {va4.x, va4.y, va4.z, va4.w};
            uint32_t cv[4] = {vc4.x, vc4.y, vc4.z, vc4.w};
#pragma unroll
            for (int j = 0; j < 4; j++) {
                uint32_t lo = (av[j] & 0xffffu) | (cv[j] << 16);
                uint32_t hi = (av[j] >> 16) | (cv[j] & 0xffff0000u);
                int hd0 = hseg * 8 + 2 * j, hd1 = hd0 + 1;
                *(uint32_t*)(Vt + hd0 * 64 + (((kp >> 2) ^ (hd0 & 7)) * 8) + (kp & 3) * 2) = lo;
                *(uint32_t*)(Vt + hd1 * 64 + (((kp >> 2) ^ (hd1 & 7)) * 8) + (kp & 3) * 2) = hi;
            }
        }

        __syncthreads();   // (B) Vt ready; K prefetch drained (vmcnt0 at barrier)

        // (7) O^T += V^T . P^T
#pragma unroll
        for (int mt = 0; mt < 4; mt++)
#pragma unroll
            for (int qt = 0; qt < 2; qt++)
#pragma unroll
                for (int r = 0; r < 4; r++) o[mt][qt][r] *= al[qt];
#pragma unroll
        for (int kk = 0; kk < 2; kk++) {
            bf16x8 vaf[4], pbf[2];
#pragma unroll
            for (int mt = 0; mt < 4; mt++)
                vaf[mt] = *(const bf16x8*)(Vt + (mt * 16 + l16) * 64 + ((kk * 4 + quad) ^ sw) * 8);
#pragma unroll
            for (int qt = 0; qt < 2; qt++) {
                int row = qt * 16 + l16;
                pbf[qt] = *(const bf16x8*)(Pw + row * 64 + (((kk * 4 + quad) ^ (row & 7)) * 8));
            }
#pragma unroll
            for (int mt = 0; mt < 4; mt++)
#pragma unroll
                for (int qt = 0; qt < 2; qt++)
                    o[mt][qt] = __builtin_amdgcn_mfma_f32_16x16x32_bf16(
                        vaf[mt], pbf[qt], o[mt][qt], 0, 0, 0);
        }
        __syncthreads();   // (C) PV reads done before next iter's Vt writes
        cur ^= 1;
    }

    // ---- output ----
    if (slot < 0) {
        // final: normalize, write ctx
#pragma unroll
        for (int qt = 0; qt < 2; qt++) {
            float inv = 1.0f / l_run[qt];
            int q = b * 128 + wave * 32 + qt * 16 + l16;
#pragma unroll
            for (int mt = 0; mt < 4; mt++) {
                ushort4 pko;
                pko.x = f2bf(o[mt][qt][0] * inv);
                pko.y = f2bf(o[mt][qt][1] * inv);
                pko.z = f2bf(o[mt][qt][2] * inv);
                pko.w = f2bf(o[mt][qt][3] * inv);
                *(ushort4*)(Og + (size_t)q * 1024 + hoff + mt * 16 + quad * 4) = pko;
            }
        }
    } else {
        // partial: unnormalized O (bf16) + (m,l) f32
        uint16_t* po = pO + (size_t)slot * 8192;
#pragma unroll
        for (int qt = 0; qt < 2; qt++) {
            int q = wave * 32 + qt * 16 + l16;
            if (quad == 0) pStats[slot * 128 + q] = make_float2(m_run[qt], l_run[qt]);
#pragma unroll
            for (int mt = 0; mt < 4; mt++) {
                ushort4 pko;
                pko.x = f2bf(o[mt][qt][0]);
                pko.y = f2bf(o[mt][qt][1]);
                pko.z = f2bf(o[mt][qt][2]);
                pko.w = f2bf(o[mt][qt][3]);
                *(ushort4*)(po + q * 64 + mt * 16 + quad * 4) = pko;
            }
        }
    }
}

// ---------------- merge two partials (b>=8) --------------------------------
__global__ __launch_bounds__(256) void attn_merge(const uint16_t* __restrict__ pO,
                                                  const float2* __restrict__ pStats,
                                                  uint16_t* __restrict__ Og) {
    const int b = 8 + blockIdx.x, h = blockIdx.y;
    const int tid = threadIdx.x;
    const int q = tid >> 1, hh = tid & 1;   // 32 hd per thread
    const int s0 = ((b - 8) * 2) * 16 + h, s1 = s0 + 16;
    float2 st0 = pStats[s0 * 128 + q];
    float2 st1 = pStats[s1 * 128 + q];
    float m = fmaxf(st0.x, st1.x);
    float f0 = exp2f(st0.x - m), f1 = exp2f(st1.x - m);
    float inv = 1.0f / (st0.y * f0 + st1.y * f1);
    f0 *= inv; f1 *= inv;
    const uint16_t* p0 = pO + (size_t)s0 * 8192 + q * 64 + hh * 32;
    const uint16_t* p1 = pO + (size_t)s1 * 8192 + q * 64 + hh * 32;
    uint16_t* od = Og + (size_t)(b * 128 + q) * 1024 + h * 64 + hh * 32;
#pragma unroll
    for (int i = 0; i < 4; i++) {
        uint4 a = *(const uint4*)(p0 + i * 8);
        uint4 c = *(const uint4*)(p1 + i * 8);
        uint32_t av[4] = {a.x, a.y, a.z, a.w}, cv[4] = {c.x, c.y, c.z, c.w};
        uint32_t ov[4];
#pragma unroll
        for (int j = 0; j < 4; j++) {
            float r0 = bf2f((uint16_t)(av[j] & 0xffffu)) * f0 + bf2f((uint16_t)(cv[j] & 0xffffu)) * f1;
            float r1 = bf2f((uint16_t)(av[j] >> 16)) * f0 + bf2f((uint16_t)(cv[j] >> 16)) * f1;
            ov[j] = pack2bf(r0, r1);
        }
        uint4 w = {ov[0], ov[1], ov[2], ov[3]};
        *(uint4*)(od + i * 8) = w;
    }
}

// ---------------------------------------------------------------------------
extern "C" void kernel_launch(void* const* d_in, const int* in_sizes, int n_in,
                              void* d_out, int out_size, void* d_ws, size_t ws_size,
                              hipStream_t stream) {
    const float* x  = (const float*)d_in[0];
    const float* Wq = (const float*)d_in[1];
    const float* bq = (const float*)d_in[2];
    const float* Wk = (const float*)d_in[3];
    const float* bk = (const float*)d_in[4];
    const float* Wv = (const float*)d_in[5];
    const float* bv = (const float*)d_in[6];
    const float* Wo = (const float*)d_in[7];
    const float* bo = (const float*)d_in[8];
    float* out = (float*)d_out;

    uint8_t* ws = (uint8_t*)d_ws;
    uint16_t* x_bf  = (uint16_t*)(ws);                       // 8 MiB (dead after gemm0)
    uint16_t* wqkvt = (uint16_t*)(ws + (8u << 20));          // 6 MiB (dead after gemm0)
    uint16_t* wot   = (uint16_t*)(ws + (14u << 20));         // 2 MiB
    uint16_t* q_bf  = (uint16_t*)(ws + (16u << 20));         // 8 MiB
    uint16_t* k_bf  = (uint16_t*)(ws + (24u << 20));
    uint16_t* v_bf  = (uint16_t*)(ws + (32u << 20));
    uint16_t* ctx   = (uint16_t*)(ws + (40u << 20));         // 8 MiB
    // partial buffers overlap x_bf/wqkvt (dead after gemm0):
    uint16_t* pO    = (uint16_t*)(ws);                       // 768*8192*2B = 12.6 MiB
    float2*   pSt   = (float2*)(ws + (13u << 20));           // 768*128*8B  = 0.77 MiB
    if (ws_size < (48u << 20)) return;

    cvt_x_kernel<<<4096, 256, 0, stream>>>(x, x_bf);
    tpose4<<<dim3(16, 16, 4), 256, 0, stream>>>(Wq, Wk, Wv, Wo, wqkvt, wot);
    gemm_bt<0><<<dim3(24, 32), 256, 0, stream>>>(x_bf, wqkvt, bq, bk, bv,
                                                 q_bf, nullptr);
    attn_kernel<<<dim3(56, 16), 256, 0, stream>>>(q_bf, k_bf, v_bf, ctx, pO, pSt);
    attn_merge<<<dim3(24, 16), 256, 0, stream>>>(pO, pSt, ctx);
    gemm_bt<1><<<dim3(8, 32), 256, 0, stream>>>(ctx, wot, bo, nullptr, nullptr,
                                                nullptr, out);
}